// Round 9
// baseline (140.970 us; speedup 1.0000x reference)
//
#include <hip/hip_runtime.h>

// QuantizedWeight dequant:
//   out[g*8+j] = (cb[0, codes[g,0], j] + cb[1, codes[g,1], j]) * scales[g] + zeros[g]
//
// r9: software-pipeline the r8 structure across super-iterations.
//   - double-buffered per-wave LDS (2 x 4 KB): codes int2[256] + s[256] + z[256]
//   - two named gather register sets A/B (8 x vi4 each); gathers for iter t+1
//     are ISSUED before iter t is consumed -> gathers in flight continuously
//   - loop unrolled x2 with named sets (no runtime-indexed reg arrays)
//   - proven pieces kept: fp16 codebook repack in d_ws (entry = 1 dwordx4),
//     pair-lane role split + shfl_xor half-exchange, half-wave split s/z
//     streams, dense 16 B/lane nt stores, __launch_bounds__(256,4).

typedef float    vf4 __attribute__((ext_vector_type(4)));
typedef int      vi4 __attribute__((ext_vector_type(4)));
typedef int      vi2 __attribute__((ext_vector_type(2)));
typedef _Float16 vh2 __attribute__((ext_vector_type(2)));
typedef _Float16 vh8 __attribute__((ext_vector_type(8)));

// ---------------- repack: f32 codebooks -> fp16 copy in workspace ----------
__global__ __launch_bounds__(256) void
repack_kernel(const float* __restrict__ cbs, _Float16* __restrict__ cb16)
{
    const int i = blockIdx.x * blockDim.x + threadIdx.x;   // 131072 threads
    const vf4* in4 = (const vf4*)cbs;
    vf4 a = in4[2 * i];
    vf4 b = in4[2 * i + 1];
    vh8 h;
    h[0] = (_Float16)a.x; h[1] = (_Float16)a.y;
    h[2] = (_Float16)a.z; h[3] = (_Float16)a.w;
    h[4] = (_Float16)b.x; h[5] = (_Float16)b.y;
    h[6] = (_Float16)b.z; h[7] = (_Float16)b.w;
    *(vh8*)(cb16 + (size_t)8 * i) = h;
}

// ---------------- pipeline building blocks ----------------------------------
struct GSet { vi4 e0, e1, e2, e3, e4, e5, e6, e7; };

__device__ __forceinline__ void
load_stream(const vi4* codes4, const float* szsrc, int lane, int sl, long gb,
            vi4& pc0, vi4& pc1, vf4& psz0, vf4& psz1)
{
    pc0  = __builtin_nontemporal_load(codes4 + (gb >> 1) + lane);
    pc1  = __builtin_nontemporal_load(codes4 + (gb >> 1) + 64 + lane);
    psz0 = __builtin_nontemporal_load((const vf4*)(szsrc + gb) + sl);
    psz1 = __builtin_nontemporal_load((const vf4*)(szsrc + gb) + 32 + sl);
}

__device__ __forceinline__ void
stage(char* buf, int lane, int szoff, vi4 pc0, vi4 pc1, vf4 psz0, vf4 psz1)
{
    *(vi4*)(buf + lane * 16)        = pc0;
    *(vi4*)(buf + 1024 + lane * 16) = pc1;
    *(vf4*)(buf + szoff)            = psz0;
    *(vf4*)(buf + szoff + 512)      = psz1;
}

__device__ __forceinline__ vi4
gload(const _Float16* cb16, int k)
{
    return *(const vi4*)(cb16 + ((size_t)(unsigned)k << 3));
}

__device__ __forceinline__ void
issue_gathers(const char* buf, int half, int pidx, const _Float16* cb16, GSet& g)
{
    vi2 c0 = *(const vi2*)(buf + (0 * 32 + pidx) * 8);
    vi2 c1 = *(const vi2*)(buf + (1 * 32 + pidx) * 8);
    vi2 c2 = *(const vi2*)(buf + (2 * 32 + pidx) * 8);
    vi2 c3 = *(const vi2*)(buf + (3 * 32 + pidx) * 8);
    vi2 c4 = *(const vi2*)(buf + (4 * 32 + pidx) * 8);
    vi2 c5 = *(const vi2*)(buf + (5 * 32 + pidx) * 8);
    vi2 c6 = *(const vi2*)(buf + (6 * 32 + pidx) * 8);
    vi2 c7 = *(const vi2*)(buf + (7 * 32 + pidx) * 8);
    g.e0 = gload(cb16, half ? (c0.y | 65536) : c0.x);
    g.e1 = gload(cb16, half ? (c1.y | 65536) : c1.x);
    g.e2 = gload(cb16, half ? (c2.y | 65536) : c2.x);
    g.e3 = gload(cb16, half ? (c3.y | 65536) : c3.x);
    g.e4 = gload(cb16, half ? (c4.y | 65536) : c4.x);
    g.e5 = gload(cb16, half ? (c5.y | 65536) : c5.x);
    g.e6 = gload(cb16, half ? (c6.y | 65536) : c6.x);
    g.e7 = gload(cb16, half ? (c7.y | 65536) : c7.x);
}

__device__ __forceinline__ void
consume_one(vi4 e, const char* buf, int k, int half, int pidx, float* ob)
{
    // exchange halves within the lane pair (even lane: cb0 entry, odd: cb1)
    int send0 = half ? e.x : e.z;
    int send1 = half ? e.y : e.w;
    int own0  = half ? e.z : e.x;
    int own1  = half ? e.w : e.y;
    int recv0 = __shfl_xor(send0, 1);
    int recv1 = __shfl_xor(send1, 1);
    vh2 s0 = __builtin_bit_cast(vh2, own0) + __builtin_bit_cast(vh2, recv0);
    vh2 s1 = __builtin_bit_cast(vh2, own1) + __builtin_bit_cast(vh2, recv1);

    float s = *(const float*)(buf + 2048 + (k * 32 + pidx) * 4);
    float z = *(const float*)(buf + 3072 + (k * 32 + pidx) * 4);
    vf4 r;
    r.x = (float)s0.x * s + z;
    r.y = (float)s0.y * s + z;
    r.z = (float)s1.x * s + z;
    r.w = (float)s1.y * s + z;
    __builtin_nontemporal_store(r, (vf4*)(ob + k * 256));
}

__device__ __forceinline__ void
consume_all(const GSet& g, const char* buf, int half, int pidx, float* ob)
{
    consume_one(g.e0, buf, 0, half, pidx, ob);
    consume_one(g.e1, buf, 1, half, pidx, ob);
    consume_one(g.e2, buf, 2, half, pidx, ob);
    consume_one(g.e3, buf, 3, half, pidx, ob);
    consume_one(g.e4, buf, 4, half, pidx, ob);
    consume_one(g.e5, buf, 5, half, pidx, ob);
    consume_one(g.e6, buf, 6, half, pidx, ob);
    consume_one(g.e7, buf, 7, half, pidx, ob);
}

// ---------------- main pipelined kernel -------------------------------------
__global__ __launch_bounds__(256, 4) void
dequant_fp16(const int* __restrict__ codes,
             const _Float16* __restrict__ cb16,   // [2][65536][8] fp16
             const float* __restrict__ cbs,       // f32 original (tail only)
             const float* __restrict__ scales,
             const float* __restrict__ zeros,
             float* __restrict__ out,
             int total)
{
    // 4 waves x 2 buffers x 4 KB = 32 KB/block
    __shared__ __align__(16) char lds_raw[4 * 8192];
    const int lane = threadIdx.x & 63;
    const int wid  = threadIdx.x >> 6;
    char* buf0 = lds_raw + wid * 8192;
    char* buf1 = buf0 + 4096;

    const int  nwaves = (gridDim.x * blockDim.x) >> 6;
    const int  wave   = (blockIdx.x * blockDim.x + threadIdx.x) >> 6;
    const long wstep  = (long)nwaves * 256;

    const vi4* codes4 = (const vi4*)codes;
    const int half = lane & 1;
    const int hoff = half * 4;
    const int pidx = lane >> 1;

    const float* szsrc = (lane < 32) ? scales : zeros;
    const int    sl    = lane & 31;
    const int    szoff = 2048 + ((lane >> 5) << 10) + (sl << 4);

    const long base = (long)wave * 256;
    long nit = 0;
    if (base + 256 <= total) nit = (total - base - 256) / wstep + 1;

    if (nit > 0) {
        vi4 pc0, pc1; vf4 psz0, psz1;
        GSet A, B;

        // prologue: iter0 staged + gathers issued; iter1 streams prefetched
        load_stream(codes4, szsrc, lane, sl, base, pc0, pc1, psz0, psz1);
        stage(buf0, lane, szoff, pc0, pc1, psz0, psz1);
        if (nit > 1)
            load_stream(codes4, szsrc, lane, sl, base + wstep, pc0, pc1, psz0, psz1);
        issue_gathers(buf0, half, pidx, cb16, A);

        long t = 0;
        for (; t + 2 <= nit; t += 2) {
            // ---- iter t (set A, buf0 in flight) ----
            stage(buf1, lane, szoff, pc0, pc1, psz0, psz1);          // iter t+1
            if (t + 2 < nit)
                load_stream(codes4, szsrc, lane, sl, base + (t + 2) * wstep,
                            pc0, pc1, psz0, psz1);
            issue_gathers(buf1, half, pidx, cb16, B);                // iter t+1
            consume_all(A, buf0, half, pidx,
                        out + (size_t)(base + t * wstep) * 8 + pidx * 8 + hoff);

            // ---- iter t+1 (set B, buf1 in flight) ----
            if (t + 2 < nit) {
                stage(buf0, lane, szoff, pc0, pc1, psz0, psz1);      // iter t+2
                if (t + 3 < nit)
                    load_stream(codes4, szsrc, lane, sl, base + (t + 3) * wstep,
                                pc0, pc1, psz0, psz1);
                issue_gathers(buf0, half, pidx, cb16, A);            // iter t+2
            }
            consume_all(B, buf1, half, pidx,
                        out + (size_t)(base + (t + 1) * wstep) * 8 + pidx * 8 + hoff);
        }
        if (t < nit) {   // odd nit: last set A (from buf0) still in flight
            consume_all(A, buf0, half, pidx,
                        out + (size_t)(base + t * wstep) * 8 + pidx * 8 + hoff);
        }
    }

    // tail: groups beyond the last full 256-chunk (none at this size; safety)
    const size_t CB1 = (size_t)65536 * 8;
    const long total_full = ((long)total >> 8) << 8;
    const int  gtid  = blockIdx.x * blockDim.x + threadIdx.x;
    const long pstep = (long)(gridDim.x * blockDim.x) >> 1;
    for (long g = total_full + (gtid >> 1); g < total; g += pstep) {
        vi2  c = *(const vi2*)(codes + (size_t)2 * g);
        float s = scales[g];
        float z = zeros[g];
        vf4 a0 = *(const vf4*)(cbs + ((size_t)c.x << 3) + hoff);
        vf4 a1 = *(const vf4*)(cbs + CB1 + ((size_t)c.y << 3) + hoff);
        vf4 r  = (a0 + a1) * s + z;
        __builtin_nontemporal_store(r, (vf4*)(out + (size_t)g * 8 + hoff));
    }
}

// ---------------- fallback (ws too small): r4 pair kernel -------------------
__global__ __launch_bounds__(256) void
dequant_f32(const int* __restrict__ codes,
            const float* __restrict__ cbs,
            const float* __restrict__ scales,
            const float* __restrict__ zeros,
            float* __restrict__ out,
            int total)
{
    const size_t CB1 = (size_t)65536 * 8;
    const vi2* codes2 = (const vi2*)codes;
    const int tid   = blockIdx.x * blockDim.x + threadIdx.x;
    const int half  = tid & 1;
    const int hoff  = half * 4;
    const int gstep = (gridDim.x * blockDim.x) >> 1;
    for (int g = tid >> 1; g < total; g += gstep) {
        vi2  c = __builtin_nontemporal_load(codes2 + g);
        float s = __builtin_nontemporal_load(scales + g);
        float z = __builtin_nontemporal_load(zeros + g);
        vf4 e0 = *(const vf4*)(cbs + ((size_t)c.x << 3) + hoff);
        vf4 e1 = *(const vf4*)(cbs + CB1 + ((size_t)c.y << 3) + hoff);
        vf4 r  = (e0 + e1) * s + z;
        __builtin_nontemporal_store(r, (vf4*)(out + (size_t)g * 8 + hoff));
    }
}

extern "C" void kernel_launch(void* const* d_in, const int* in_sizes, int n_in,
                              void* d_out, int out_size, void* d_ws, size_t ws_size,
                              hipStream_t stream) {
    const int*   codes     = (const int*)  d_in[0];
    const float* codebooks = (const float*)d_in[1];
    const float* scales    = (const float*)d_in[2];
    const float* zeros     = (const float*)d_in[3];
    float*       out       = (float*)d_out;

    const int total = in_sizes[0] / 2;           // number of groups
    const size_t cb16_bytes = (size_t)2 * 65536 * 8 * sizeof(_Float16); // 2 MB

    if (ws_size >= cb16_bytes) {
        _Float16* cb16 = (_Float16*)d_ws;
        repack_kernel<<<512, 256, 0, stream>>>(codebooks, cb16);
        dequant_fp16<<<2048, 256, 0, stream>>>(
            codes, cb16, codebooks, scales, zeros, out, total);
    } else {
        dequant_f32<<<2048, 256, 0, stream>>>(
            codes, codebooks, scales, zeros, out, total);
    }
}

// Round 10
// 127.552 us; speedup vs baseline: 1.1052x; 1.1052x over previous
//
#include <hip/hip_runtime.h>

// QuantizedWeight dequant:
//   out[g*8+j] = (cb[0, codes[g,0], j] + cb[1, codes[g,1], j]) * scales[g] + zeros[g]
//
// r10: r8 structure (single LDS buffer per wave, stage -> prefetch -> gather
// -> consume, proven 133 us) with ONE change: gather MLP depth 8 -> 16.
//   - wave owns 512 consecutive groups per super-iteration
//   - 16 gathers issued back-to-back into 16 NAMED vi4 regs (one set -> no
//     r9-style dual-set register blowup), consumed in issue order
//   - per-lane pre-offset codebook base removes the |65536 per gather
//   - kept: fp16 codebook repack in d_ws, pair-lane role split + shfl_xor
//     half exchange, half-wave split s/z streams, dense 16 B/lane nt stores,
//     __launch_bounds__(256,4).

typedef float    vf4 __attribute__((ext_vector_type(4)));
typedef int      vi4 __attribute__((ext_vector_type(4)));
typedef int      vi2 __attribute__((ext_vector_type(2)));
typedef _Float16 vh2 __attribute__((ext_vector_type(2)));
typedef _Float16 vh8 __attribute__((ext_vector_type(8)));

// ---------------- repack: f32 codebooks -> fp16 copy in workspace ----------
__global__ __launch_bounds__(256) void
repack_kernel(const float* __restrict__ cbs, _Float16* __restrict__ cb16)
{
    const int i = blockIdx.x * blockDim.x + threadIdx.x;   // 131072 threads
    const vf4* in4 = (const vf4*)cbs;
    vf4 a = in4[2 * i];
    vf4 b = in4[2 * i + 1];
    vh8 h;
    h[0] = (_Float16)a.x; h[1] = (_Float16)a.y;
    h[2] = (_Float16)a.z; h[3] = (_Float16)a.w;
    h[4] = (_Float16)b.x; h[5] = (_Float16)b.y;
    h[6] = (_Float16)b.z; h[7] = (_Float16)b.w;
    *(vh8*)(cb16 + (size_t)8 * i) = h;
}

// ---------------- main fp16-gather kernel, 16-deep MLP ----------------------
__global__ __launch_bounds__(256, 4) void
dequant_fp16(const int* __restrict__ codes,
             const _Float16* __restrict__ cb16,   // [2][65536][8] fp16
             const float* __restrict__ cbs,       // f32 original (tail only)
             const float* __restrict__ scales,
             const float* __restrict__ zeros,
             float* __restrict__ out,
             int total)
{
    // per-wave 8 KB: [0,4096) codes int2[512]; [4096,6144) s[512]; [6144,8192) z[512]
    __shared__ __align__(16) char lds_raw[4 * 8192];
    const int lane = threadIdx.x & 63;
    const int wid  = threadIdx.x >> 6;
    char* wlds = lds_raw + wid * 8192;

    const int  nwaves = (gridDim.x * blockDim.x) >> 6;
    const int  wave   = (blockIdx.x * blockDim.x + threadIdx.x) >> 6;
    const long wstep  = (long)nwaves * 512;

    const vi4* codes4 = (const vi4*)codes;

    const int half = lane & 1;            // output half AND entry role
    const int hoff = half * 4;            // float offset of my output half
    const int pidx = lane >> 1;           // pair index 0..31
    const _Float16* mycb = cb16 + ((size_t)half << 19);  // cb1 base for odd lanes

    const float* szsrc = (lane < 32) ? scales : zeros;
    const int    sl    = lane & 31;
    char* szdst = wlds + 4096 + ((lane >> 5) << 11) + (sl << 4);

    long gbase = (long)wave * 512;

    if (gbase + 512 <= total) {
        // prologue stream loads (cover 512 groups)
        vi4 pc0  = __builtin_nontemporal_load(codes4 + (gbase >> 1) + lane);
        vi4 pc1  = __builtin_nontemporal_load(codes4 + (gbase >> 1) + 64 + lane);
        vi4 pc2  = __builtin_nontemporal_load(codes4 + (gbase >> 1) + 128 + lane);
        vi4 pc3  = __builtin_nontemporal_load(codes4 + (gbase >> 1) + 192 + lane);
        vf4 psz0 = __builtin_nontemporal_load((const vf4*)(szsrc + gbase) + sl);
        vf4 psz1 = __builtin_nontemporal_load((const vf4*)(szsrc + gbase) + 32 + sl);
        vf4 psz2 = __builtin_nontemporal_load((const vf4*)(szsrc + gbase) + 64 + sl);
        vf4 psz3 = __builtin_nontemporal_load((const vf4*)(szsrc + gbase) + 96 + sl);

        for (;;) {
            const long gcur = gbase;
            gbase += wstep;
            const bool more = (gbase + 512 <= total);

            // stage current super-iteration (wave-synchronous, in-order DS)
            *(vi4*)(wlds + lane * 16)        = pc0;
            *(vi4*)(wlds + 1024 + lane * 16) = pc1;
            *(vi4*)(wlds + 2048 + lane * 16) = pc2;
            *(vi4*)(wlds + 3072 + lane * 16) = pc3;
            *(vf4*)szdst                     = psz0;
            *(vf4*)(szdst + 512)             = psz1;
            *(vf4*)(szdst + 1024)            = psz2;
            *(vf4*)(szdst + 1536)            = psz3;

            // prefetch next super-iteration's streams
            if (more) {
                pc0  = __builtin_nontemporal_load(codes4 + (gbase >> 1) + lane);
                pc1  = __builtin_nontemporal_load(codes4 + (gbase >> 1) + 64 + lane);
                pc2  = __builtin_nontemporal_load(codes4 + (gbase >> 1) + 128 + lane);
                pc3  = __builtin_nontemporal_load(codes4 + (gbase >> 1) + 192 + lane);
                psz0 = __builtin_nontemporal_load((const vf4*)(szsrc + gbase) + sl);
                psz1 = __builtin_nontemporal_load((const vf4*)(szsrc + gbase) + 32 + sl);
                psz2 = __builtin_nontemporal_load((const vf4*)(szsrc + gbase) + 64 + sl);
                psz3 = __builtin_nontemporal_load((const vf4*)(szsrc + gbase) + 96 + sl);
            }

            // ---- 16 code reads (pair-broadcast, 2-way = free) ----
            vi2 c0  = *(const vi2*)(wlds + (0  * 32 + pidx) * 8);
            vi2 c1  = *(const vi2*)(wlds + (1  * 32 + pidx) * 8);
            vi2 c2  = *(const vi2*)(wlds + (2  * 32 + pidx) * 8);
            vi2 c3  = *(const vi2*)(wlds + (3  * 32 + pidx) * 8);
            vi2 c4  = *(const vi2*)(wlds + (4  * 32 + pidx) * 8);
            vi2 c5  = *(const vi2*)(wlds + (5  * 32 + pidx) * 8);
            vi2 c6  = *(const vi2*)(wlds + (6  * 32 + pidx) * 8);
            vi2 c7  = *(const vi2*)(wlds + (7  * 32 + pidx) * 8);
            vi2 c8  = *(const vi2*)(wlds + (8  * 32 + pidx) * 8);
            vi2 c9  = *(const vi2*)(wlds + (9  * 32 + pidx) * 8);
            vi2 c10 = *(const vi2*)(wlds + (10 * 32 + pidx) * 8);
            vi2 c11 = *(const vi2*)(wlds + (11 * 32 + pidx) * 8);
            vi2 c12 = *(const vi2*)(wlds + (12 * 32 + pidx) * 8);
            vi2 c13 = *(const vi2*)(wlds + (13 * 32 + pidx) * 8);
            vi2 c14 = *(const vi2*)(wlds + (14 * 32 + pidx) * 8);
            vi2 c15 = *(const vi2*)(wlds + (15 * 32 + pidx) * 8);

            // ---- 16 gathers back-to-back into named regs (16-deep MLP) ----
            vi4 e0  = *(const vi4*)(mycb + ((size_t)(unsigned)(half ? c0.y  : c0.x)  << 3));
            vi4 e1  = *(const vi4*)(mycb + ((size_t)(unsigned)(half ? c1.y  : c1.x)  << 3));
            vi4 e2  = *(const vi4*)(mycb + ((size_t)(unsigned)(half ? c2.y  : c2.x)  << 3));
            vi4 e3  = *(const vi4*)(mycb + ((size_t)(unsigned)(half ? c3.y  : c3.x)  << 3));
            vi4 e4  = *(const vi4*)(mycb + ((size_t)(unsigned)(half ? c4.y  : c4.x)  << 3));
            vi4 e5  = *(const vi4*)(mycb + ((size_t)(unsigned)(half ? c5.y  : c5.x)  << 3));
            vi4 e6  = *(const vi4*)(mycb + ((size_t)(unsigned)(half ? c6.y  : c6.x)  << 3));
            vi4 e7  = *(const vi4*)(mycb + ((size_t)(unsigned)(half ? c7.y  : c7.x)  << 3));
            vi4 e8  = *(const vi4*)(mycb + ((size_t)(unsigned)(half ? c8.y  : c8.x)  << 3));
            vi4 e9  = *(const vi4*)(mycb + ((size_t)(unsigned)(half ? c9.y  : c9.x)  << 3));
            vi4 e10 = *(const vi4*)(mycb + ((size_t)(unsigned)(half ? c10.y : c10.x) << 3));
            vi4 e11 = *(const vi4*)(mycb + ((size_t)(unsigned)(half ? c11.y : c11.x) << 3));
            vi4 e12 = *(const vi4*)(mycb + ((size_t)(unsigned)(half ? c12.y : c12.x) << 3));
            vi4 e13 = *(const vi4*)(mycb + ((size_t)(unsigned)(half ? c13.y : c13.x) << 3));
            vi4 e14 = *(const vi4*)(mycb + ((size_t)(unsigned)(half ? c14.y : c14.x) << 3));
            vi4 e15 = *(const vi4*)(mycb + ((size_t)(unsigned)(half ? c15.y : c15.x) << 3));

            float* ob = out + (size_t)gcur * 8 + pidx * 8 + hoff;

            // ---- consume in issue order (staged vmcnt waits) ----
            #pragma unroll
            for (int k = 0; k < 16; ++k) {
                vi4 e = (k == 0)  ? e0  : (k == 1)  ? e1  : (k == 2)  ? e2  :
                        (k == 3)  ? e3  : (k == 4)  ? e4  : (k == 5)  ? e5  :
                        (k == 6)  ? e6  : (k == 7)  ? e7  : (k == 8)  ? e8  :
                        (k == 9)  ? e9  : (k == 10) ? e10 : (k == 11) ? e11 :
                        (k == 12) ? e12 : (k == 13) ? e13 : (k == 14) ? e14 : e15;
                // exchange halves within the lane pair (even: cb0, odd: cb1)
                int send0 = half ? e.x : e.z;
                int send1 = half ? e.y : e.w;
                int own0  = half ? e.z : e.x;
                int own1  = half ? e.w : e.y;
                int recv0 = __shfl_xor(send0, 1);
                int recv1 = __shfl_xor(send1, 1);
                vh2 s0 = __builtin_bit_cast(vh2, own0) + __builtin_bit_cast(vh2, recv0);
                vh2 s1 = __builtin_bit_cast(vh2, own1) + __builtin_bit_cast(vh2, recv1);

                float s = *(const float*)(wlds + 4096 + (k * 32 + pidx) * 4);
                float z = *(const float*)(wlds + 6144 + (k * 32 + pidx) * 4);
                vf4 r;
                r.x = (float)s0.x * s + z;
                r.y = (float)s0.y * s + z;
                r.z = (float)s1.x * s + z;
                r.w = (float)s1.y * s + z;
                __builtin_nontemporal_store(r, (vf4*)(ob + k * 256));
            }
            if (!more) break;
        }
    }

    // tail: groups beyond the last full 512-chunk (none at this size; safety)
    const size_t CB1 = (size_t)65536 * 8;
    const long total_full = ((long)total >> 9) << 9;
    const int  gtid  = blockIdx.x * blockDim.x + threadIdx.x;
    const long pstep = (long)(gridDim.x * blockDim.x) >> 1;
    for (long g = total_full + (gtid >> 1); g < total; g += pstep) {
        vi2  c = *(const vi2*)(codes + (size_t)2 * g);
        float s = scales[g];
        float z = zeros[g];
        vf4 a0 = *(const vf4*)(cbs + ((size_t)c.x << 3) + hoff);
        vf4 a1 = *(const vf4*)(cbs + CB1 + ((size_t)c.y << 3) + hoff);
        vf4 r  = (a0 + a1) * s + z;
        __builtin_nontemporal_store(r, (vf4*)(out + (size_t)g * 8 + hoff));
    }
}

// ---------------- fallback (ws too small): r4 pair kernel -------------------
__global__ __launch_bounds__(256) void
dequant_f32(const int* __restrict__ codes,
            const float* __restrict__ cbs,
            const float* __restrict__ scales,
            const float* __restrict__ zeros,
            float* __restrict__ out,
            int total)
{
    const size_t CB1 = (size_t)65536 * 8;
    const vi2* codes2 = (const vi2*)codes;
    const int tid   = blockIdx.x * blockDim.x + threadIdx.x;
    const int half  = tid & 1;
    const int hoff  = half * 4;
    const int gstep = (gridDim.x * blockDim.x) >> 1;
    for (int g = tid >> 1; g < total; g += gstep) {
        vi2  c = __builtin_nontemporal_load(codes2 + g);
        float s = __builtin_nontemporal_load(scales + g);
        float z = __builtin_nontemporal_load(zeros + g);
        vf4 e0 = *(const vf4*)(cbs + ((size_t)c.x << 3) + hoff);
        vf4 e1 = *(const vf4*)(cbs + CB1 + ((size_t)c.y << 3) + hoff);
        vf4 r  = (e0 + e1) * s + z;
        __builtin_nontemporal_store(r, (vf4*)(out + (size_t)g * 8 + hoff));
    }
}

extern "C" void kernel_launch(void* const* d_in, const int* in_sizes, int n_in,
                              void* d_out, int out_size, void* d_ws, size_t ws_size,
                              hipStream_t stream) {
    const int*   codes     = (const int*)  d_in[0];
    const float* codebooks = (const float*)d_in[1];
    const float* scales    = (const float*)d_in[2];
    const float* zeros     = (const float*)d_in[3];
    float*       out       = (float*)d_out;

    const int total = in_sizes[0] / 2;           // number of groups
    const size_t cb16_bytes = (size_t)2 * 65536 * 8 * sizeof(_Float16); // 2 MB

    if (ws_size >= cb16_bytes) {
        _Float16* cb16 = (_Float16*)d_ws;
        repack_kernel<<<512, 256, 0, stream>>>(codebooks, cb16);
        dequant_fp16<<<2048, 256, 0, stream>>>(
            codes, cb16, codebooks, scales, zeros, out, total);
    } else {
        dequant_f32<<<2048, 256, 0, stream>>>(
            codes, codebooks, scales, zeros, out, total);
    }
}